// Round 11
// baseline (162.310 us; speedup 1.0000x reference)
//
#include <hip/hip_runtime.h>
#include <stdint.h>

#define B_ 16
#define N_ 25200
#define NC_ 80
#define ROW_ 85
#define TOPK_ 1024
#define MAXDET_ 300
#define CONF_T 0.25f
#define IOU_T 0.45f
#define MAX_WH_ 4096.0f
#define NBINS_ 16384   /* LDS histogram of key bits [44:58) == conf bits [12:26) */
#define CBUF_CAP 4096

typedef unsigned long long u64;
typedef unsigned int u32;

// ws layout: only keys now (select+NMS is fully fused; no T / obox / pay).
#define OFF_KEYS  0ull                      // 16*25200*8 = 3,225,600

// ---------------------------------------------------------------------------
// K1: persistent blocks + double-buffered global_load_lds DMA (proven R8/R10).
// key = conf_bits<<32 | (0xFFFFFFFF - n)  (unique; desc order == lax.top_k)
// ---------------------------------------------------------------------------
#define K1_ROWS 64
#define K1_TPB  ((N_ + K1_ROWS - 1) / K1_ROWS)    /* 394 tiles per batch  */
#define K1_TILES (K1_TPB * B_)                    /* 6304 tiles total     */
#define K1_GRID 768                               /* 3 blocks/CU x 256 CU */
#define K1_SLOTS 24                               /* 6 per wave x 4 waves  */
#define K1_BUF_F4 (K1_SLOTS * 64)                 /* 1536 float4 buffer    */

__device__ __forceinline__ void k1_stage(const float4* __restrict__ src4, int cnt4,
                                         float4* buf, int wid, int lane) {
#pragma unroll
    for (int k = 0; k < 6; ++k) {
        const int s = k * 4 + wid;                 // slot 0..23
        const int f = s * 64 + lane;
        const float4* g = src4 + min(f, cnt4 - 1); // clamp: never read past det
        float4* l = buf + s * 64;                  // wave-uniform, in-bounds
        __builtin_amdgcn_global_load_lds(
            (const __attribute__((address_space(1))) void*)g,
            (__attribute__((address_space(3))) void*)l, 16, 0, 0);
    }
}

__global__ void __launch_bounds__(256) score_kernel(const float* __restrict__ det,
                                                    u64* __restrict__ keys) {
#pragma clang fp contract(off)
    __shared__ float4 sbuf[2 * K1_BUF_F4];         // 49,152 B -> 3 blocks/CU
    const int t = threadIdx.x;
    const int wid = t >> 6;
    const int lane = t & 63;

    int tid = blockIdx.x;
    {
        const int b0 = tid / K1_TPB, tk0 = tid % K1_TPB;
        const int r00 = tk0 * K1_ROWS;
        const int rows0 = min(K1_ROWS, N_ - r00);
        const float4* src4 = (const float4*)(det + ((size_t)b0 * N_ + r00) * ROW_);
        k1_stage(src4, rows0 * ROW_ / 4, &sbuf[0], wid, lane);
    }
    int p = 0;
    while (tid < K1_TILES) {
        const int b = tid / K1_TPB, tk = tid % K1_TPB;
        const int r0 = tk * K1_ROWS;
        const int rows = min(K1_ROWS, N_ - r0);
        const int next = tid + K1_GRID;
        if (next < K1_TILES) {
            const int nb = next / K1_TPB, ntk = next % K1_TPB;
            const int nr0 = ntk * K1_ROWS;
            const int nrows = min(K1_ROWS, N_ - nr0);
            const float4* nsrc4 = (const float4*)(det + ((size_t)nb * N_ + nr0) * ROW_);
            k1_stage(nsrc4, nrows * ROW_ / 4, &sbuf[(1 - p) * K1_BUF_F4], wid, lane);
            asm volatile("s_waitcnt vmcnt(6)" ::: "memory");  // current tile done
        } else {
            asm volatile("s_waitcnt vmcnt(0)" ::: "memory");
        }
        __builtin_amdgcn_sched_barrier(0);
        __builtin_amdgcn_s_barrier();

        const float* sp = (const float*)&sbuf[p * K1_BUF_F4];
        const int row = t >> 2;
        const int h = t & 3;
        const bool rv = (row < rows);
        float m = -1.0f;
        float obj = 0.0f;
        if (rv) {
            const float* rp = sp + row * ROW_;
            obj = rp[4];
#pragma unroll
            for (int c = 0; c < 20; ++c) {
                float pr = obj * rp[5 + h * 20 + c];
                m = (pr > m) ? pr : m;
            }
        }
        m = fmaxf(m, __shfl_xor(m, 1));
        m = fmaxf(m, __shfl_xor(m, 2));
        float conf = (rv && obj > CONF_T && m > CONF_T) ? m : 0.0f;
        u64 key = ((u64)__float_as_uint(conf) << 32) |
                  (u32)(0xFFFFFFFFu - (u32)(r0 + row));
        if (rv && h == 0) keys[(size_t)b * N_ + r0 + row] = key;

        __builtin_amdgcn_s_barrier();  // all reads of buf[p] done before re-stage
        p ^= 1;
        tid = next;
    }
}

// ---------------------------------------------------------------------------
// K2: select + sort + gather + NMS + output, fully fused. One 1024-thr block
// per batch. Select phases A-F byte-identical to the proven R8 kernel; the
// NMS replaces the global T matrix with on-demand IoU into LDS:
//   per word sw: 1024 threads compute tc[s][c] (rows word s -> column
//   sw*64+c) for s<=sw from LDS boxes; wave 0 runs the proven ballot
//   fixpoint; early-terminate once >=300 kept (scores descending).
// tc stored TRANSPOSED [16][64] so wave-0 reads tc[q][lane] are stride-8B
// (2-way bank aliasing = free; row-major would be 64-way, G4).
// nms region (29 KB) aliases hist16k/cbuf (dead after D); sorted untouched.
// ---------------------------------------------------------------------------
__global__ void __launch_bounds__(1024) select_nms_kernel(const u64* __restrict__ keys,
                                                          const float* __restrict__ det,
                                                          float* __restrict__ out) {
#pragma clang fp contract(off)
    const int b = blockIdx.x;
    const int t = threadIdx.x;
    const int lane = t & 63;
    const int wid = t >> 6;
    __shared__ union {
        struct {
            u32 hist[NBINS_];            // 65,536 B
            u64 cbuf[CBUF_CAP];          // 32,768 B
            u64 sorted[TOPK_];           //  8,192 B  (offset 98,304)
            u32 hist256[256];            //  1,024 B
            u32 wtot[16];                //     64 B
        } sel;
        struct {                         // 28,928 B — aliases hist/cbuf only
            float4 sbox[TOPK_];          // 16,384 B
            float  sar[TOPK_];           //  4,096 B
            u64    tc[16][64];           //  8,192 B (transposed)
            u64    keptw[16];            //    128 B
            u64    validw[16];           //    128 B
        } nms;
    } S;
    __shared__ u64 s_prefix;
    __shared__ int s_k, s_cnt, s_cutd, s_total, s_done, s_kept;

    const u64* bkeys = keys + (size_t)b * N_;

    // ---- A: LDS 16K-bin histogram of nonzero keys ----
    for (int i = t; i < NBINS_; i += 1024) S.sel.hist[i] = 0;
    __syncthreads();
    for (int n = t; n < N_; n += 1024) {
        u64 key = bkeys[n];
        if ((key >> 32) != 0)
            atomicAdd(&S.sel.hist[(u32)(key >> 44) & (NBINS_ - 1)], 1u);
    }
    __syncthreads();

    // ---- B: suffix scan -> coarse cutd ----
    u32 h[16];
    u32 csum = 0;
#pragma unroll
    for (int q = 0; q < 16; ++q) { h[q] = S.sel.hist[t * 16 + q]; csum += h[q]; }
    u32 suf = csum;
#pragma unroll
    for (int off = 1; off < 64; off <<= 1) {
        u32 v = __shfl_down(suf, off);
        if (lane + off < 64) suf += v;
    }
    if (lane == 0) S.sel.wtot[wid] = suf;
    __syncthreads();
    if (t == 0) {
        u32 tot = 0;
        for (int w = 0; w < 16; ++w) tot += S.sel.wtot[w];
        s_total = (int)tot;
        s_cutd = 0;
    }
    __syncthreads();
    u32 hi = 0;
    for (int w = wid + 1; w < 16; ++w) hi += S.sel.wtot[w];
    u32 above = (suf - csum) + hi;
    u32 incl = above + csum;
    if (incl >= (u32)TOPK_ && above < (u32)TOPK_) {
        u32 cum = above;
        int cutd = t * 16;
        bool found = false;
#pragma unroll
        for (int q = 15; q >= 0; --q) {
            if (!found && cum + h[q] >= (u32)TOPK_) { cutd = t * 16 + q; found = true; }
            if (!found) cum += h[q];
        }
        s_cutd = cutd;
    }
    __syncthreads();
    const u32 cutd = (u32)s_cutd;
    const int total = s_total;

    // ---- C: compact candidates into LDS (4x unrolled) ----
    if (t == 0) s_cnt = 0;
    __syncthreads();
    {
        int n = t;
        for (; n + 3 * 1024 < N_; n += 4096) {
            u64 k0 = bkeys[n];
            u64 k1 = bkeys[n + 1024];
            u64 k2 = bkeys[n + 2048];
            u64 k3 = bkeys[n + 3072];
            if ((k0 >> 32) != 0 && ((u32)(k0 >> 44) & (NBINS_ - 1)) >= cutd) { int p = atomicAdd(&s_cnt, 1); if (p < CBUF_CAP) S.sel.cbuf[p] = k0; }
            if ((k1 >> 32) != 0 && ((u32)(k1 >> 44) & (NBINS_ - 1)) >= cutd) { int p = atomicAdd(&s_cnt, 1); if (p < CBUF_CAP) S.sel.cbuf[p] = k1; }
            if ((k2 >> 32) != 0 && ((u32)(k2 >> 44) & (NBINS_ - 1)) >= cutd) { int p = atomicAdd(&s_cnt, 1); if (p < CBUF_CAP) S.sel.cbuf[p] = k2; }
            if ((k3 >> 32) != 0 && ((u32)(k3 >> 44) & (NBINS_ - 1)) >= cutd) { int p = atomicAdd(&s_cnt, 1); if (p < CBUF_CAP) S.sel.cbuf[p] = k3; }
        }
        for (; n < N_; n += 1024) {
            u64 key = bkeys[n];
            if ((key >> 32) != 0 && ((u32)(key >> 44) & (NBINS_ - 1)) >= cutd) { int p = atomicAdd(&s_cnt, 1); if (p < CBUF_CAP) S.sel.cbuf[p] = key; }
        }
    }
    __syncthreads();
    const int cnt = min(s_cnt, CBUF_CAP);

    if (total >= TOPK_) {
        // ---- D: exact radix select of 1024th-largest among cbuf ----
        u64 prefix = 0;
        int k = TOPK_;
        for (int shift = 56; shift >= 0; shift -= 8) {
            if (t < 256) S.sel.hist256[t] = 0;
            __syncthreads();
            for (int nn = t; nn < cnt; nn += 1024) {
                u64 key = S.sel.cbuf[nn];
                if (shift == 56 || (key >> (shift + 8)) == prefix)
                    atomicAdd(&S.sel.hist256[(u32)(key >> shift) & 255u], 1u);
            }
            __syncthreads();
            if (t < 64) {
                u32 b0 = S.sel.hist256[t * 4 + 0], b1 = S.sel.hist256[t * 4 + 1];
                u32 b2 = S.sel.hist256[t * 4 + 2], b3 = S.sel.hist256[t * 4 + 3];
                u32 sgrp = b0 + b1 + b2 + b3;
                u32 sufl = sgrp;
#pragma unroll
                for (int off = 1; off < 64; off <<= 1) {
                    u32 vv = __shfl(sufl, t + off);
                    sufl += (t + off < 64) ? vv : 0;
                }
                u32 A = sufl - sgrp;
                if (sufl >= (u32)k && A < (u32)k) {
                    u32 cum = A;
                    int d = t * 4;
                    bool found = false;
                    if (!found && cum + b3 >= (u32)k) { d = t * 4 + 3; found = true; }
                    if (!found) { cum += b3; if (cum + b2 >= (u32)k) { d = t * 4 + 2; found = true; } }
                    if (!found) { cum += b2; if (cum + b1 >= (u32)k) { d = t * 4 + 1; found = true; } }
                    if (!found) { cum += b1; if (cum + b0 >= (u32)k) { d = t * 4 + 0; found = true; } }
                    s_prefix = (prefix << 8) | (u64)d;
                    s_k = k - (int)cum;
                }
            }
            __syncthreads();
            prefix = s_prefix;
            k = s_k;
            __syncthreads();
        }
        const u64 T64 = prefix;

        if (t == 0) s_cnt = 0;
        __syncthreads();
        for (int nn = t; nn < cnt; nn += 1024) {
            u64 key = S.sel.cbuf[nn];
            if (key >= T64) {
                int pos = atomicAdd(&s_cnt, 1);
                if (pos < TOPK_) S.sel.sorted[pos] = key;
            }
        }
        __syncthreads();
    } else {
        // fallback (<1024 valid): real keys + conf=0 fillers (valid=0:
        // never output, never suppress — matches reference padding)
        for (int i = t; i < TOPK_; i += 1024)
            S.sel.sorted[i] = (i < cnt) ? S.sel.cbuf[i]
                                        : (u64)(u32)(0xFFFFFFFFu - (u32)i);
        __syncthreads();
    }

    // ---- E: bitonic sort descending (unique keys -> exact total order) ----
    for (int kk = 2; kk <= TOPK_; kk <<= 1) {
        for (int j = kk >> 1; j > 0; j >>= 1) {
            __syncthreads();
            int partner = t ^ j;
            if (partner > t) {
                u64 a = S.sel.sorted[t], c = S.sel.sorted[partner];
                bool desc = ((t & kk) == 0);
                if (desc ? (a < c) : (a > c)) { S.sel.sorted[t] = c; S.sel.sorted[partner] = a; }
            }
        }
    }
    __syncthreads();

    // ---- F: rank t = thread t: gather row, recompute (reference FP order),
    //         stash boxes in LDS + payload in registers ----
    u64 myk = S.sel.sorted[t];
    int n_idx = (int)(0xFFFFFFFFu - (u32)myk);
    float conf = __uint_as_float((u32)(myk >> 32));
    const float* row = det + ((size_t)b * N_ + n_idx) * ROW_;
    float xc = row[0], yc = row[1], w = row[2], hh2 = row[3];
    float obj = row[4];
    float m = -1.0f;
    int cls = 0;
    for (int c = 0; c < NC_; ++c) {
        float p = obj * row[5 + c];
        if (p > m) { m = p; cls = c; }   // strict > == jnp.argmax first-max
    }
    float hw = w * 0.5f, hh = hh2 * 0.5f;
    float x1 = xc - hw, y1 = yc - hh, x2 = xc + hw, y2 = yc + hh;
    float off = (float)cls * MAX_WH_;
    float X1 = x1 + off, Y1 = y1 + off, X2 = x2 + off, Y2 = y2 + off;
    float area = fmaxf(X2 - X1, 0.0f) * fmaxf(Y2 - Y1, 0.0f);

    // nms region aliases hist/cbuf (both dead); sorted (offset 96K) untouched
    S.nms.sbox[t] = make_float4(X1, Y1, X2, Y2);
    S.nms.sar[t] = area;
    u64 vb = __ballot(conf > 0.0f);
    if (lane == 0) S.nms.validw[wid] = vb;
    if (t < 16) S.nms.keptw[t] = 0;
    if (t == 0) { s_done = 0; s_kept = 0; }
    __syncthreads();

    // ---- G: NMS, word-by-word with on-demand IoU + early termination ----
    const int c_ = t >> 4;               // column-in-word 0..63
    const int s_ = t & 15;               // row-word slot 0..15
    for (int sw = 0; sw < 16; ++sw) {
        if (s_ <= sw) {                  // compute tc[s_][c_] for word sw
            const int j = sw * 64 + c_;
            const float4 bj = S.nms.sbox[j];
            const float aj = S.nms.sar[j];
            u64 mm = 0;
#pragma unroll 4
            for (int jj = 0; jj < 64; ++jj) {
                int r = (jj + 5 * s_) & 63;      // stagger LDS broadcast groups
                int i = (s_ << 6) | r;
                float4 bi = S.nms.sbox[i];
                float ai = S.nms.sar[i];
                float lx = fmaxf(bi.x, bj.x);
                float ly = fmaxf(bi.y, bj.y);
                float rx = fminf(bi.z, bj.z);
                float ry = fminf(bi.w, bj.w);
                float iw = fmaxf(rx - lx, 0.0f);
                float ih = fmaxf(ry - ly, 0.0f);
                float inter = iw * ih;
                float uni = ai + aj - inter + 1e-7f;  // ((ai+aj)-inter)+1e-7
                bool sup = (inter / uni > IOU_T) && (j > i);
                mm |= sup ? (1ull << r) : 0ull;
            }
            S.nms.tc[s_][c_] = mm;
        }
        __syncthreads();
        if (t < 64) {                    // wave 0: proven ballot fixpoint
            u64 rem_in = 0;
            for (int q = 0; q < sw; ++q) {
                u64 kq = S.nms.keptw[q];          // uniform broadcast
                u64 tq = S.nms.tc[q][lane];       // stride-8B: 2-way, free
                rem_in |= __ballot((kq & tq) != 0);
            }
            u64 Td = S.nms.tc[sw][lane];
            u64 vw = S.nms.validw[sw];
            u64 K = 0;
            u64 R = (~vw) | rem_in;
            u64 U = ~(K | R);
            int guard = 0;
            while (U && guard++ < 64) {
                u64 Sx = Td & (K | U);
                bool inU = ((U >> lane) & 1ull) != 0;
                u64 nK = __ballot(inU && (Sx == 0));
                u64 nR = __ballot(inU && ((Sx & K) != 0));
                K |= nK;
                R |= nR;
                U &= ~(nK | nR);
            }
            if (lane == 0) {
                S.nms.keptw[sw] = K;
                int tot = s_kept + __popcll(K);
                s_kept = tot;
                if (tot >= MAXDET_) s_done = 1;   // later ranks can't output
            }
        }
        __syncthreads();
        if (s_done) break;               // uniform after barrier
    }

    // ---- H: compacted output write + zero tail ----
    u64 kw = S.nms.keptw[wid];
    bool keptbit = ((kw >> lane) & 1ull) != 0;
    int rank = __popcll(kw & ((1ull << lane) - 1ull));
    for (int q = 0; q < 16; ++q)
        if (q < wid) rank += __popcll(S.nms.keptw[q]);
    if (keptbit && rank < MAXDET_) {
        float* o = out + ((size_t)b * MAXDET_ + rank) * 6;
        o[0] = x1; o[1] = y1; o[2] = x2; o[3] = y2;
        o[4] = conf; o[5] = (float)cls;
    }
    int totk = 0;
    for (int q = 0; q < 16; ++q) totk += __popcll(S.nms.keptw[q]);
    int kept_n = totk < MAXDET_ ? totk : MAXDET_;
    for (int i = kept_n * 6 + t; i < MAXDET_ * 6; i += 1024)
        out[(size_t)b * MAXDET_ * 6 + i] = 0.0f;
}

extern "C" void kernel_launch(void* const* d_in, const int* in_sizes, int n_in,
                              void* d_out, int out_size, void* d_ws, size_t ws_size,
                              hipStream_t stream) {
    const float* det = (const float*)d_in[0];
    float* out = (float*)d_out;
    char* ws = (char*)d_ws;

    u64* keys = (u64*)(ws + OFF_KEYS);

    score_kernel<<<K1_GRID, 256, 0, stream>>>(det, keys);
    select_nms_kernel<<<B_, 1024, 0, stream>>>(keys, det, out);
}

// Round 12
// 92.584 us; speedup vs baseline: 1.7531x; 1.7531x over previous
//
#include <hip/hip_runtime.h>
#include <stdint.h>

#define B_ 16
#define N_ 25200
#define NC_ 80
#define ROW_ 85
#define TOPK_ 1024
#define MAXDET_ 300
#define CONF_T 0.25f
#define IOU_T 0.45f
#define MAX_WH_ 4096.0f
#define NBINS_ 16384   /* LDS histogram of key bits [44:58) == conf bits [12:26) */
#define CBUF_CAP 4096

typedef unsigned long long u64;
typedef unsigned int u32;

// ws layout (bytes). T (2 MB) ALIASES keys (3.2 MB): keys dead after select,
// mask runs after it (separate graph node).
#define OFF_KEYS  0ull                      // 16*25200*8 = 3,225,600
#define OFF_T     0ull                      // 16*1024*16*8 = 2,097,152 (alias)
#define OFF_OBOX  3225600ull                // 16*1024*16 =   262,144
#define OFF_OAR   3487744ull                // 16*1024*4  =    65,536
#define OFF_PAY   3553280ull                // 16*1024*24 =   393,216
#define OFF_VALID 3946496ull                // 16*1024*4  =    65,536  -> end 4,012,032

// ---------------------------------------------------------------------------
// K1: persistent blocks + double-buffered global_load_lds DMA (proven R8).
// key = conf_bits<<32 | (0xFFFFFFFF - n)  (unique; desc order == lax.top_k)
// ---------------------------------------------------------------------------
#define K1_ROWS 64
#define K1_TPB  ((N_ + K1_ROWS - 1) / K1_ROWS)    /* 394 tiles per batch  */
#define K1_TILES (K1_TPB * B_)                    /* 6304 tiles total     */
#define K1_GRID 768                               /* 3 blocks/CU x 256 CU */
#define K1_SLOTS 24                               /* 6 per wave x 4 waves  */
#define K1_BUF_F4 (K1_SLOTS * 64)                 /* 1536 float4 buffer    */

__device__ __forceinline__ void k1_stage(const float4* __restrict__ src4, int cnt4,
                                         float4* buf, int wid, int lane) {
#pragma unroll
    for (int k = 0; k < 6; ++k) {
        const int s = k * 4 + wid;                 // slot 0..23
        const int f = s * 64 + lane;
        const float4* g = src4 + min(f, cnt4 - 1); // clamp: never read past det
        float4* l = buf + s * 64;                  // wave-uniform, in-bounds
        __builtin_amdgcn_global_load_lds(
            (const __attribute__((address_space(1))) void*)g,
            (__attribute__((address_space(3))) void*)l, 16, 0, 0);
    }
}

__global__ void __launch_bounds__(256) score_kernel(const float* __restrict__ det,
                                                    u64* __restrict__ keys) {
#pragma clang fp contract(off)
    __shared__ float4 sbuf[2 * K1_BUF_F4];         // 49,152 B -> 3 blocks/CU
    const int t = threadIdx.x;
    const int wid = t >> 6;
    const int lane = t & 63;

    int tid = blockIdx.x;
    {
        const int b0 = tid / K1_TPB, tk0 = tid % K1_TPB;
        const int r00 = tk0 * K1_ROWS;
        const int rows0 = min(K1_ROWS, N_ - r00);
        const float4* src4 = (const float4*)(det + ((size_t)b0 * N_ + r00) * ROW_);
        k1_stage(src4, rows0 * ROW_ / 4, &sbuf[0], wid, lane);
    }
    int p = 0;
    while (tid < K1_TILES) {
        const int b = tid / K1_TPB, tk = tid % K1_TPB;
        const int r0 = tk * K1_ROWS;
        const int rows = min(K1_ROWS, N_ - r0);
        const int next = tid + K1_GRID;
        if (next < K1_TILES) {
            const int nb = next / K1_TPB, ntk = next % K1_TPB;
            const int nr0 = ntk * K1_ROWS;
            const int nrows = min(K1_ROWS, N_ - nr0);
            const float4* nsrc4 = (const float4*)(det + ((size_t)nb * N_ + nr0) * ROW_);
            k1_stage(nsrc4, nrows * ROW_ / 4, &sbuf[(1 - p) * K1_BUF_F4], wid, lane);
            asm volatile("s_waitcnt vmcnt(6)" ::: "memory");  // current tile done
        } else {
            asm volatile("s_waitcnt vmcnt(0)" ::: "memory");
        }
        __builtin_amdgcn_sched_barrier(0);
        __builtin_amdgcn_s_barrier();

        const float* sp = (const float*)&sbuf[p * K1_BUF_F4];
        const int row = t >> 2;
        const int h = t & 3;
        const bool rv = (row < rows);
        float m = -1.0f;
        float obj = 0.0f;
        if (rv) {
            const float* rp = sp + row * ROW_;
            obj = rp[4];
#pragma unroll
            for (int c = 0; c < 20; ++c) {
                float pr = obj * rp[5 + h * 20 + c];
                m = (pr > m) ? pr : m;
            }
        }
        m = fmaxf(m, __shfl_xor(m, 1));
        m = fmaxf(m, __shfl_xor(m, 2));
        float conf = (rv && obj > CONF_T && m > CONF_T) ? m : 0.0f;
        u64 key = ((u64)__float_as_uint(conf) << 32) |
                  (u32)(0xFFFFFFFFu - (u32)(r0 + row));
        if (rv && h == 0) keys[(size_t)b * N_ + r0 + row] = key;

        __builtin_amdgcn_s_barrier();  // all reads of buf[p] done before re-stage
        p ^= 1;
        tid = next;
    }
}

// ---------------------------------------------------------------------------
// K2: select + sort + gather (R8-proven structure). One 1024-thr block per
// batch. Micro-opts vs R8: (1) phase-A key pass unrolled x4 (independent
// loads in flight); (2) hybrid bitonic — shfl_xor for j<64 (no barriers),
// LDS exchange only for j>=64. Same compare network -> identical result.
// ---------------------------------------------------------------------------
__global__ void __launch_bounds__(1024) select_kernel(const u64* __restrict__ keys,
                                                      const float* __restrict__ det,
                                                      float4* __restrict__ obox4,
                                                      float* __restrict__ oar,
                                                      float* __restrict__ pay,
                                                      int* __restrict__ valid) {
#pragma clang fp contract(off)
    const int b = blockIdx.x;
    const int t = threadIdx.x;
    const int lane = t & 63;
    const int wid = t >> 6;
    __shared__ u32 hist16k[NBINS_];      // 64 KB
    __shared__ u64 cbuf[CBUF_CAP];       // 32 KB
    __shared__ u64 sorted[TOPK_];        // 8 KB
    __shared__ u32 hist256[256];
    __shared__ u32 wtot[16];
    __shared__ u64 s_prefix;
    __shared__ int s_k, s_cnt, s_cutd, s_total;

    const u64* bkeys = keys + (size_t)b * N_;

    // ---- A: LDS 16K-bin histogram of nonzero keys (4x unrolled) ----
    for (int i = t; i < NBINS_; i += 1024) hist16k[i] = 0;
    __syncthreads();
    {
        int n = t;
        for (; n + 3 * 1024 < N_; n += 4096) {
            u64 k0 = bkeys[n];
            u64 k1 = bkeys[n + 1024];
            u64 k2 = bkeys[n + 2048];
            u64 k3 = bkeys[n + 3072];
            if ((k0 >> 32) != 0) atomicAdd(&hist16k[(u32)(k0 >> 44) & (NBINS_ - 1)], 1u);
            if ((k1 >> 32) != 0) atomicAdd(&hist16k[(u32)(k1 >> 44) & (NBINS_ - 1)], 1u);
            if ((k2 >> 32) != 0) atomicAdd(&hist16k[(u32)(k2 >> 44) & (NBINS_ - 1)], 1u);
            if ((k3 >> 32) != 0) atomicAdd(&hist16k[(u32)(k3 >> 44) & (NBINS_ - 1)], 1u);
        }
        for (; n < N_; n += 1024) {
            u64 key = bkeys[n];
            if ((key >> 32) != 0)
                atomicAdd(&hist16k[(u32)(key >> 44) & (NBINS_ - 1)], 1u);
        }
    }
    __syncthreads();

    // ---- B: suffix scan -> coarse cutd ----
    u32 h[16];
    u32 csum = 0;
#pragma unroll
    for (int q = 0; q < 16; ++q) { h[q] = hist16k[t * 16 + q]; csum += h[q]; }
    u32 suf = csum;
#pragma unroll
    for (int off = 1; off < 64; off <<= 1) {
        u32 v = __shfl_down(suf, off);
        if (lane + off < 64) suf += v;
    }
    if (lane == 0) wtot[wid] = suf;
    __syncthreads();
    if (t == 0) {
        u32 tot = 0;
        for (int w = 0; w < 16; ++w) tot += wtot[w];
        s_total = (int)tot;
        s_cutd = 0;
    }
    __syncthreads();
    u32 hi = 0;
    for (int w = wid + 1; w < 16; ++w) hi += wtot[w];
    u32 above = (suf - csum) + hi;
    u32 incl = above + csum;
    if (incl >= (u32)TOPK_ && above < (u32)TOPK_) {
        u32 cum = above;
        int cutd = t * 16;
        bool found = false;
#pragma unroll
        for (int q = 15; q >= 0; --q) {
            if (!found && cum + h[q] >= (u32)TOPK_) { cutd = t * 16 + q; found = true; }
            if (!found) cum += h[q];
        }
        s_cutd = cutd;
    }
    __syncthreads();
    const u32 cutd = (u32)s_cutd;
    const int total = s_total;

    // ---- C: compact candidates into LDS (4x unrolled) ----
    if (t == 0) s_cnt = 0;
    __syncthreads();
    {
        int n = t;
        for (; n + 3 * 1024 < N_; n += 4096) {
            u64 k0 = bkeys[n];
            u64 k1 = bkeys[n + 1024];
            u64 k2 = bkeys[n + 2048];
            u64 k3 = bkeys[n + 3072];
            if ((k0 >> 32) != 0 && ((u32)(k0 >> 44) & (NBINS_ - 1)) >= cutd) { int p = atomicAdd(&s_cnt, 1); if (p < CBUF_CAP) cbuf[p] = k0; }
            if ((k1 >> 32) != 0 && ((u32)(k1 >> 44) & (NBINS_ - 1)) >= cutd) { int p = atomicAdd(&s_cnt, 1); if (p < CBUF_CAP) cbuf[p] = k1; }
            if ((k2 >> 32) != 0 && ((u32)(k2 >> 44) & (NBINS_ - 1)) >= cutd) { int p = atomicAdd(&s_cnt, 1); if (p < CBUF_CAP) cbuf[p] = k2; }
            if ((k3 >> 32) != 0 && ((u32)(k3 >> 44) & (NBINS_ - 1)) >= cutd) { int p = atomicAdd(&s_cnt, 1); if (p < CBUF_CAP) cbuf[p] = k3; }
        }
        for (; n < N_; n += 1024) {
            u64 key = bkeys[n];
            if ((key >> 32) != 0 && ((u32)(key >> 44) & (NBINS_ - 1)) >= cutd) { int p = atomicAdd(&s_cnt, 1); if (p < CBUF_CAP) cbuf[p] = key; }
        }
    }
    __syncthreads();
    const int cnt = min(s_cnt, CBUF_CAP);

    if (total >= TOPK_) {
        // ---- D: exact radix select of 1024th-largest among cbuf ----
        u64 prefix = 0;
        int k = TOPK_;
        for (int shift = 56; shift >= 0; shift -= 8) {
            if (t < 256) hist256[t] = 0;
            __syncthreads();
            for (int nn = t; nn < cnt; nn += 1024) {
                u64 key = cbuf[nn];
                if (shift == 56 || (key >> (shift + 8)) == prefix)
                    atomicAdd(&hist256[(u32)(key >> shift) & 255u], 1u);
            }
            __syncthreads();
            if (t < 64) {
                u32 b0 = hist256[t * 4 + 0], b1 = hist256[t * 4 + 1];
                u32 b2 = hist256[t * 4 + 2], b3 = hist256[t * 4 + 3];
                u32 sgrp = b0 + b1 + b2 + b3;
                u32 sufl = sgrp;
#pragma unroll
                for (int off = 1; off < 64; off <<= 1) {
                    u32 vv = __shfl(sufl, t + off);
                    sufl += (t + off < 64) ? vv : 0;
                }
                u32 A = sufl - sgrp;
                if (sufl >= (u32)k && A < (u32)k) {
                    u32 cum = A;
                    int d = t * 4;
                    bool found = false;
                    if (!found && cum + b3 >= (u32)k) { d = t * 4 + 3; found = true; }
                    if (!found) { cum += b3; if (cum + b2 >= (u32)k) { d = t * 4 + 2; found = true; } }
                    if (!found) { cum += b2; if (cum + b1 >= (u32)k) { d = t * 4 + 1; found = true; } }
                    if (!found) { cum += b1; if (cum + b0 >= (u32)k) { d = t * 4 + 0; found = true; } }
                    s_prefix = (prefix << 8) | (u64)d;
                    s_k = k - (int)cum;
                }
            }
            __syncthreads();
            prefix = s_prefix;
            k = s_k;
            __syncthreads();
        }
        const u64 T64 = prefix;

        if (t == 0) s_cnt = 0;
        __syncthreads();
        for (int nn = t; nn < cnt; nn += 1024) {
            u64 key = cbuf[nn];
            if (key >= T64) {
                int pos = atomicAdd(&s_cnt, 1);
                if (pos < TOPK_) sorted[pos] = key;
            }
        }
        __syncthreads();
    } else {
        for (int i = t; i < TOPK_; i += 1024)
            sorted[i] = (i < cnt) ? cbuf[i] : (u64)(u32)(0xFFFFFFFFu - (u32)i);
        __syncthreads();
    }

    // ---- E: hybrid bitonic sort descending (register + shfl for j<64) ----
    u64 v = sorted[t];
    for (int kk = 2; kk <= TOPK_; kk <<= 1) {
        const bool desc = ((t & kk) == 0);
        for (int j = kk >> 1; j > 0; j >>= 1) {
            u64 w;
            if (j >= 64) {
                __syncthreads();
                sorted[t] = v;
                __syncthreads();
                w = sorted[t ^ j];
            } else {
                w = __shfl_xor(v, j);
            }
            const bool up = (t & j) == 0;
            const bool takeMax = (desc == up);
            v = takeMax ? (v > w ? v : w) : (v < w ? v : w);
        }
    }
    // v = rank-t key (descending); no write-back needed

    // ---- F: rank t = thread t: gather row, recompute, write ----
    u64 myk = v;
    int n_idx = (int)(0xFFFFFFFFu - (u32)myk);
    float conf = __uint_as_float((u32)(myk >> 32));
    const float* row = det + ((size_t)b * N_ + n_idx) * ROW_;
    float xc = row[0], yc = row[1], w2 = row[2], hh2 = row[3];
    float obj = row[4];
    float m = -1.0f;
    int cls = 0;
    for (int c = 0; c < NC_; ++c) {
        float p = obj * row[5 + c];
        if (p > m) { m = p; cls = c; }   // strict > == jnp.argmax first-max
    }
    float hw = w2 * 0.5f, hh = hh2 * 0.5f;
    float x1 = xc - hw, y1 = yc - hh, x2 = xc + hw, y2 = yc + hh;
    float off = (float)cls * MAX_WH_;
    float X1 = x1 + off, Y1 = y1 + off, X2 = x2 + off, Y2 = y2 + off;
    float area = fmaxf(X2 - X1, 0.0f) * fmaxf(Y2 - Y1, 0.0f);

    size_t o = (size_t)b * TOPK_ + t;
    obox4[o] = make_float4(X1, Y1, X2, Y2);
    oar[o] = area;
    float* p6 = pay + o * 6;
    p6[0] = x1; p6[1] = y1; p6[2] = x2; p6[3] = y2;
    p6[4] = conf; p6[5] = (float)cls;
    valid[o] = (conf > 0.0f) ? 1 : 0;
}

// ---------------------------------------------------------------------------
// K3: TRANSPOSED suppression matrix (unchanged, 1024 blocks -> full device).
// T[j][w] bit r = row i=w*64+r suppresses column j: (j>i) && iou>IOU_T.
// Reference FP order: uni = ((ai+aj)-inter)+1e-7; iou = inter/uni.
// ---------------------------------------------------------------------------
__global__ void __launch_bounds__(256) mask_kernel(const float4* __restrict__ obox4,
                                                   const float* __restrict__ oar,
                                                   u64* __restrict__ T) {
#pragma clang fp contract(off)
    __shared__ float4 sbox[TOPK_];
    __shared__ float sar[TOPK_];
    const int b = blockIdx.y;
    const int t = threadIdx.x;
    for (int i = t; i < TOPK_; i += 256) {
        sbox[i] = obox4[(size_t)b * TOPK_ + i];
        sar[i] = oar[(size_t)b * TOPK_ + i];
    }
    __syncthreads();
    const int j = blockIdx.x * 16 + (t >> 4);   // column
    const int w = t & 15;                       // row word
    float4 bj = sbox[j];
    float aj = sar[j];
    u64 m = 0;
#pragma unroll 4
    for (int jj = 0; jj < 64; ++jj) {
        int r = (jj + 5 * w) & 63;              // stagger LDS broadcast groups
        int i = (w << 6) | r;
        float4 bi = sbox[i];
        float ai = sar[i];
        float lx = fmaxf(bi.x, bj.x);
        float ly = fmaxf(bi.y, bj.y);
        float rx = fminf(bi.z, bj.z);
        float ry = fminf(bi.w, bj.w);
        float iw = fmaxf(rx - lx, 0.0f);
        float ih = fmaxf(ry - ly, 0.0f);
        float inter = iw * ih;
        float uni = ai + aj - inter + 1e-7f;
        bool sup = (inter / uni > IOU_T) && (j > i);
        m |= sup ? (1ull << r) : 0ull;
    }
    T[((size_t)b * TOPK_ + j) * 16 + w] = m;
}

// ---------------------------------------------------------------------------
// K4: word-parallel exact greedy scan, one wave per batch (unchanged).
// ---------------------------------------------------------------------------
__global__ void __launch_bounds__(64) scan_kernel(const u64* __restrict__ T,
                                                  const int* __restrict__ valid,
                                                  const float* __restrict__ pay,
                                                  float* __restrict__ out) {
    const int b = blockIdx.x;
    const int lane = threadIdx.x;
    u64 kept[16];
    bool done = false;
    int total = 0;

#pragma unroll
    for (int sw = 0; sw < 16; ++sw) {
        if (done) { kept[sw] = 0; continue; }
        const u64* col = T + ((size_t)(b * TOPK_ + sw * 64 + lane)) * 16;
        u64 tc[16];
#pragma unroll
        for (int q = 0; q < 8; ++q) {
            ulonglong2 v = reinterpret_cast<const ulonglong2*>(col)[q];
            tc[2 * q] = v.x;
            tc[2 * q + 1] = v.y;
        }
        int vint = valid[b * TOPK_ + sw * 64 + lane];
        u64 vw = __ballot(vint != 0);
        u64 rem_in = 0;
#pragma unroll
        for (int s = 0; s < 16; ++s) {
            if (s < sw) rem_in |= __ballot((kept[s] & tc[s]) != 0);
        }
        u64 Td = tc[sw];
        u64 K = 0;
        u64 R = (~vw) | rem_in;
        u64 U = ~(K | R);
        int guard = 0;
        while (U && guard++ < 64) {
            u64 Sx = Td & (K | U);
            bool inU = ((U >> lane) & 1ull) != 0;
            u64 nK = __ballot(inU && (Sx == 0));
            u64 nR = __ballot(inU && ((Sx & K) != 0));
            K |= nK;
            R |= nR;
            U &= ~(nK | nR);
        }
        kept[sw] = K;
        total += __popcll(K);
        if (total >= MAXDET_) done = true;
    }

    int cum = 0;
#pragma unroll
    for (int w = 0; w < 16; ++w) {
        u64 aw = kept[w];
        bool bit = ((aw >> lane) & 1ull) != 0;
        int rank = cum + __popcll(aw & ((1ull << lane) - 1ull));
        if (bit && rank < MAXDET_) {
            const float* p6 = pay + ((size_t)(b * TOPK_ + w * 64 + lane)) * 6;
            float* o = out + ((size_t)(b * MAXDET_ + rank)) * 6;
            o[0] = p6[0]; o[1] = p6[1]; o[2] = p6[2];
            o[3] = p6[3]; o[4] = p6[4]; o[5] = p6[5];
        }
        cum += __popcll(aw);
    }
    int kept_n = cum < MAXDET_ ? cum : MAXDET_;
    for (int i = kept_n * 6 + lane; i < MAXDET_ * 6; i += 64)
        out[(size_t)b * MAXDET_ * 6 + i] = 0.0f;
}

extern "C" void kernel_launch(void* const* d_in, const int* in_sizes, int n_in,
                              void* d_out, int out_size, void* d_ws, size_t ws_size,
                              hipStream_t stream) {
    const float* det = (const float*)d_in[0];
    float* out = (float*)d_out;
    char* ws = (char*)d_ws;

    u64* keys = (u64*)(ws + OFF_KEYS);
    u64* T = (u64*)(ws + OFF_T);       // aliases keys (dead before mask)
    float4* obox4 = (float4*)(ws + OFF_OBOX);
    float* oar = (float*)(ws + OFF_OAR);
    float* pay = (float*)(ws + OFF_PAY);
    int* valid = (int*)(ws + OFF_VALID);

    score_kernel<<<K1_GRID, 256, 0, stream>>>(det, keys);
    select_kernel<<<B_, 1024, 0, stream>>>(keys, det, obox4, oar, pay, valid);
    dim3 g3(TOPK_ / 16, B_);
    mask_kernel<<<g3, 256, 0, stream>>>(obox4, oar, T);
    scan_kernel<<<B_, 64, 0, stream>>>(T, valid, pay, out);
}